// Round 1
// baseline (956.373 us; speedup 1.0000x reference)
//
#include <hip/hip_runtime.h>
#include <hip/hip_bf16.h>
#include <stdint.h>

typedef unsigned short u16;
typedef unsigned int   u32;
typedef __attribute__((ext_vector_type(8))) short bf16x8;
typedef __attribute__((ext_vector_type(4))) float f32x4;

#define GLAS  __attribute__((address_space(1)))
#define LDSAS __attribute__((address_space(3)))

// async global->LDS, 16B per lane. LDS dest is wave-uniform base + lane*16.
__device__ __forceinline__ void gl_lds16(const void* g, void* l) {
    __builtin_amdgcn_global_load_lds((const GLAS u32*)(uintptr_t)g,
                                     (LDSAS u32*)(u32)(uintptr_t)l, 16, 0, 0);
}

// RNE fp32->bf16 (manual, no header-rounding roulette)
__device__ __forceinline__ u16 f2bf_rne(float f) {
    u32 u = __float_as_uint(f);
    u32 r = u + 0x7fffu + ((u >> 16) & 1u);
    return (u16)(r >> 16);
}
// packed pair via HIP intrinsic (v_cvt_pk_bf16_f32 on gfx950), low16 = a
__device__ __forceinline__ u32 pk_bf2(float a, float b) {
    __hip_bfloat162 h = __float22bfloat162_rn(float2{a, b});
    u32 u; __builtin_memcpy(&u, &h, 4);
    return u;
}
__device__ __forceinline__ float bfbits_lo(u32 p) { return __uint_as_float(p << 16); }
__device__ __forceinline__ float bfbits_hi(u32 p) { return __uint_as_float(p & 0xffff0000u); }

__device__ __forceinline__ void unpack8(uint4 u, float* f) {
    f[0] = bfbits_lo(u.x); f[1] = bfbits_hi(u.x);
    f[2] = bfbits_lo(u.y); f[3] = bfbits_hi(u.y);
    f[4] = bfbits_lo(u.z); f[5] = bfbits_hi(u.z);
    f[6] = bfbits_lo(u.w); f[7] = bfbits_hi(u.w);
}

// ---------------- weight transpose + convert: WT[n][k] = bf16(W[k][n]) ----------------
struct WtArgs { const float* W[4]; u16* WT[4]; };

__global__ __launch_bounds__(256) void wtrans(WtArgs a) {
    const int z = blockIdx.z;
    const float* __restrict__ W = a.W[z];
    u16* __restrict__ WT = a.WT[z];
    __shared__ float tile[64][65];
    const int n0 = blockIdx.x * 64, k0 = blockIdx.y * 64;
    const int tid = threadIdx.x;
    const int r = tid >> 6, c = tid & 63;
    #pragma unroll
    for (int p = 0; p < 16; ++p) {
        const int row = p * 4 + r;
        tile[row][c] = W[(size_t)(k0 + row) * 1024 + n0 + c];
    }
    __syncthreads();
    #pragma unroll
    for (int p = 0; p < 16; ++p) {
        const int row = p * 4 + r;   // n index within tile
        WT[(size_t)(n0 + row) * 1024 + k0 + c] = f2bf_rne(tile[c][row]);
    }
}

// ---------------- GEMM: C[m][n] = sum_k A[m][k] * BT[n][k] + bias[n] ----------------
struct GemmArgs { const void* A[3]; const void* BT[3]; const void* bias[3]; void* C[3]; };

template<bool A_F32, bool OUT_F32>
__global__ __launch_bounds__(256, 2)
void gemm_bt(GemmArgs ga, int M, int N, int K) {
    __shared__ u16 As[128 * 32];
    __shared__ u16 Bs[128 * 32];
    const int z = blockIdx.z;
    const u16*   __restrict__ BT   = (const u16*)ga.BT[z];
    const float* __restrict__ bias = (const float*)ga.bias[z];
    const int tid = threadIdx.x;
    const int lane = tid & 63;
    const int wave = tid >> 6;
    const int m0 = blockIdx.y * 128;
    const int n0 = blockIdx.x * 128;

    f32x4 acc[4][4] = {};

    const int srow = lane >> 2;        // row within 16-row chunk (bf16 gl_lds path)
    const int scol = (lane & 3) * 8;   // col within 32 (8 bf16 = 16B)

    for (int k0 = 0; k0 < K; k0 += 32) {
        // ---- stage B-tile (128x32 bf16) via async global->LDS
        #pragma unroll
        for (int cc = 0; cc < 2; ++cc) {
            const int chunk = cc * 4 + wave;
            gl_lds16(BT + (size_t)(n0 + chunk * 16 + srow) * K + (k0 + scol),
                     &Bs[chunk * 512]);
        }
        // ---- stage A-tile
        if constexpr (A_F32) {
            const float* __restrict__ A = (const float*)ga.A[z];
            float4 av[4];
            #pragma unroll
            for (int cc = 0; cc < 4; ++cc) {
                const int e = (cc * 256 + tid) * 4;
                av[cc] = *(const float4*)(A + (size_t)(m0 + (e >> 5)) * K + (k0 + (e & 31)));
            }
            #pragma unroll
            for (int cc = 0; cc < 4; ++cc) {
                const int e = (cc * 256 + tid) * 4;
                uint2 pk;
                pk.x = pk_bf2(av[cc].x, av[cc].y);
                pk.y = pk_bf2(av[cc].z, av[cc].w);
                *(uint2*)&As[(e >> 5) * 32 + (e & 31)] = pk;
            }
        } else {
            const u16* __restrict__ A = (const u16*)ga.A[z];
            #pragma unroll
            for (int cc = 0; cc < 2; ++cc) {
                const int chunk = cc * 4 + wave;
                gl_lds16(A + (size_t)(m0 + chunk * 16 + srow) * K + (k0 + scol),
                         &As[chunk * 512]);
            }
        }
        __syncthreads();

        // ---- fragments + MFMA
        const int wm = (wave >> 1) * 64;
        const int wn = (wave & 1) * 64;
        const int fr = lane & 15;
        const int fk = (lane >> 4) * 8;
        bf16x8 af[4], bfr[4];
        #pragma unroll
        for (int i = 0; i < 4; ++i) af[i]  = *(const bf16x8*)&As[(wm + i * 16 + fr) * 32 + fk];
        #pragma unroll
        for (int j = 0; j < 4; ++j) bfr[j] = *(const bf16x8*)&Bs[(wn + j * 16 + fr) * 32 + fk];
        #pragma unroll
        for (int i = 0; i < 4; ++i)
            #pragma unroll
            for (int j = 0; j < 4; ++j)
                acc[i][j] = __builtin_amdgcn_mfma_f32_16x16x32_bf16(af[i], bfr[j], acc[i][j], 0, 0, 0);
        __syncthreads();
    }

    // ---- epilogue: C/D layout col=lane&15, row=(lane>>4)*4+r
    const int wm = (wave >> 1) * 64;
    const int wn = (wave & 1) * 64;
    const int r0 = m0 + wm + (lane >> 4) * 4;
    const int c0 = n0 + wn + (lane & 15);
    #pragma unroll
    for (int j = 0; j < 4; ++j) {
        const int col = c0 + j * 16;
        const float bv = bias[col];
        #pragma unroll
        for (int i = 0; i < 4; ++i) {
            #pragma unroll
            for (int r = 0; r < 4; ++r) {
                const int row = r0 + i * 16 + r;
                const float v = acc[i][j][r] + bv;
                if constexpr (OUT_F32) ((float*)ga.C[z])[(size_t)row * N + col] = v;
                else                   ((u16*)ga.C[z])[(size_t)row * N + col] = f2bf_rne(v);
            }
        }
    }
}

// ---------------- attention over head axis, per (b, g=l/16) tile ----------------
// Q[b,l,h,d] = QL[b, h*256+g, t*64+d], l = g*16+t
__global__ __launch_bounds__(256, 2)
void attn(const u16* __restrict__ QL, const u16* __restrict__ KL, const u16* __restrict__ VL,
          u16* __restrict__ CTX, float* __restrict__ WOUT) {
    __shared__ u16 Ks[16 * 1024];
    __shared__ u16 Vs[16 * 1024];
    const int bg = blockIdx.x;
    const int b = bg >> 8, g = bg & 255;
    const int tid = threadIdx.x, lane = tid & 63, wave = tid >> 6;
    const size_t boff = (size_t)b * (4096 * 1024);

    // stage K,V tiles: 16 rows (head j) x 1024 cols; 2 chunks of 1024B per row
    for (int it = 0; it < 8; ++it) {
        const int c = it * 4 + wave;           // 0..31
        const int row = c >> 1, half = c & 1;
        const size_t gidx = boff + (size_t)(row * 256 + g) * 1024 + half * 512 + lane * 8;
        gl_lds16(KL + gidx, &Ks[c * 512]);
        gl_lds16(VL + gidx, &Vs[c * 512]);
    }
    __syncthreads();

    const int t = tid >> 4, h = tid & 15;
    // Q row into registers
    float qf[64];
    const u16* qp = QL + boff + (size_t)(h * 256 + g) * 1024 + t * 64;
    #pragma unroll
    for (int c8 = 0; c8 < 8; ++c8) {
        uint4 u = *(const uint4*)(qp + c8 * 8);
        unpack8(u, &qf[c8 * 8]);
    }
    // scores over heads j
    float s[16];
    #pragma unroll 1
    for (int j = 0; j < 16; ++j) {
        const u16* kp = &Ks[j * 1024 + t * 64];
        float a = 0.f;
        #pragma unroll
        for (int c8 = 0; c8 < 8; ++c8) {
            uint4 u = *(const uint4*)(kp + c8 * 8);
            float kf[8]; unpack8(u, kf);
            #pragma unroll
            for (int d = 0; d < 8; ++d) a = fmaf(qf[c8 * 8 + d], kf[d], a);
        }
        s[j] = a * 0.125f;  // hd^-0.5 = 1/8
    }
    // softmax over j
    float mx = s[0];
    #pragma unroll
    for (int j = 1; j < 16; ++j) mx = fmaxf(mx, s[j]);
    float w[16], sum = 0.f;
    #pragma unroll
    for (int j = 0; j < 16; ++j) { w[j] = __expf(s[j] - mx); sum += w[j]; }
    const float inv = 1.f / sum;
    #pragma unroll
    for (int j = 0; j < 16; ++j) w[j] *= inv;
    // write weights[b, l, h, j]
    {
        float4* wp = (float4*)(WOUT + ((size_t)((b * 4096 + g * 16 + t) * 16 + h) * 16));
        wp[0] = float4{w[0],  w[1],  w[2],  w[3]};
        wp[1] = float4{w[4],  w[5],  w[6],  w[7]};
        wp[2] = float4{w[8],  w[9],  w[10], w[11]};
        wp[3] = float4{w[12], w[13], w[14], w[15]};
    }
    // ctx = sum_j w[j] * V[j]
    float cx[64];
    #pragma unroll
    for (int d = 0; d < 64; ++d) cx[d] = 0.f;
    #pragma unroll 1
    for (int j = 0; j < 16; ++j) {
        const u16* vp = &Vs[j * 1024 + t * 64];
        const float wj = w[j];
        #pragma unroll
        for (int c8 = 0; c8 < 8; ++c8) {
            uint4 u = *(const uint4*)(vp + c8 * 8);
            float vf[8]; unpack8(u, vf);
            #pragma unroll
            for (int d = 0; d < 8; ++d) cx[c8 * 8 + d] = fmaf(wj, vf[d], cx[c8 * 8 + d]);
        }
    }
    // write ctx_merged[b, h*256+g, t*64+d] as bf16
    u16* cp = CTX + boff + (size_t)(h * 256 + g) * 1024 + t * 64;
    #pragma unroll
    for (int c8 = 0; c8 < 8; ++c8) {
        uint4 o;
        o.x = pk_bf2(cx[c8 * 8 + 0], cx[c8 * 8 + 1]);
        o.y = pk_bf2(cx[c8 * 8 + 2], cx[c8 * 8 + 3]);
        o.z = pk_bf2(cx[c8 * 8 + 4], cx[c8 * 8 + 5]);
        o.w = pk_bf2(cx[c8 * 8 + 6], cx[c8 * 8 + 7]);
        *(uint4*)(cp + c8 * 8) = o;
    }
}

// ---------------- host ----------------
extern "C" void kernel_launch(void* const* d_in, const int* in_sizes, int n_in,
                              void* d_out, int out_size, void* d_ws, size_t ws_size,
                              hipStream_t stream) {
    const float* q  = (const float*)d_in[0];
    const float* k  = (const float*)d_in[1];
    const float* v  = (const float*)d_in[2];
    const float* Wq = (const float*)d_in[3];
    const float* bq = (const float*)d_in[4];
    const float* Wk = (const float*)d_in[5];
    const float* bk = (const float*)d_in[6];
    const float* Wv = (const float*)d_in[7];
    const float* bv = (const float*)d_in[8];
    const float* Wo = (const float*)d_in[9];
    const float* bo = (const float*)d_in[10];

    const int M = 8 * 4096;   // 32768
    const int D = 1024;

    // workspace layout (bf16 elements): 4 x WT (1M each) + QL/KL/VL/CTX (33.5M each) = 277 MB
    u16* WT0 = (u16*)d_ws;
    u16* WT1 = WT0 + 1048576;
    u16* WT2 = WT1 + 1048576;
    u16* WT3 = WT2 + 1048576;
    u16* QL  = WT3 + 1048576;
    u16* KL  = QL + (size_t)M * D;
    u16* VL  = KL + (size_t)M * D;
    u16* CTX = VL + (size_t)M * D;

    float* out  = (float*)d_out;
    float* wout = out + (size_t)M * D;   // weights output at offset 33554432

    // 1) transpose+convert all four weight matrices
    WtArgs wa{{Wq, Wk, Wv, Wo}, {WT0, WT1, WT2, WT3}};
    wtrans<<<dim3(16, 16, 4), 256, 0, stream>>>(wa);

    // 2) QKV projections (A fp32 -> bf16 staged in-kernel), bf16 outputs
    GemmArgs g1{{q, k, v}, {WT0, WT1, WT2}, {bq, bk, bv}, {QL, KL, VL}};
    gemm_bt<true, false><<<dim3(D / 128, M / 128, 3), 256, 0, stream>>>(g1, M, D, D);

    // 3) per-position head attention + softmax weights output
    attn<<<dim3(2048), 256, 0, stream>>>(QL, KL, VL, CTX, wout);

    // 4) output projection, fp32 output
    GemmArgs g2{{CTX, nullptr, nullptr}, {WT3, nullptr, nullptr}, {bo, nullptr, nullptr}, {out, nullptr, nullptr}};
    gemm_bt<false, true><<<dim3(D / 128, M / 128, 1), 256, 0, stream>>>(g2, M, D, D);
}

// Round 2
// 918.696 us; speedup vs baseline: 1.0410x; 1.0410x over previous
//
#include <hip/hip_runtime.h>
#include <hip/hip_bf16.h>
#include <stdint.h>

typedef unsigned short u16;
typedef unsigned int   u32;
typedef __attribute__((ext_vector_type(8))) short bf16x8;
typedef __attribute__((ext_vector_type(4))) float f32x4;

#define GLAS  __attribute__((address_space(1)))
#define LDSAS __attribute__((address_space(3)))

// async global->LDS, 16B per lane. LDS dest is wave-uniform base + lane*16.
__device__ __forceinline__ void gl_lds16(const void* g, void* l) {
    __builtin_amdgcn_global_load_lds((const GLAS u32*)(uintptr_t)g,
                                     (LDSAS u32*)(u32)(uintptr_t)l, 16, 0, 0);
}

// RNE fp32->bf16
__device__ __forceinline__ u16 f2bf_rne(float f) {
    u32 u = __float_as_uint(f);
    u32 r = u + 0x7fffu + ((u >> 16) & 1u);
    return (u16)(r >> 16);
}
// packed pair (v_cvt_pk_bf16_f32 on gfx950), low16 = a
__device__ __forceinline__ u32 pk_bf2(float a, float b) {
    __hip_bfloat162 h = __float22bfloat162_rn(float2{a, b});
    u32 u; __builtin_memcpy(&u, &h, 4);
    return u;
}
__device__ __forceinline__ float bfbits_lo(u32 p) { return __uint_as_float(p << 16); }
__device__ __forceinline__ float bfbits_hi(u32 p) { return __uint_as_float(p & 0xffff0000u); }

__device__ __forceinline__ void unpack8(uint4 u, float* f) {
    f[0] = bfbits_lo(u.x); f[1] = bfbits_hi(u.x);
    f[2] = bfbits_lo(u.y); f[3] = bfbits_hi(u.y);
    f[4] = bfbits_lo(u.z); f[5] = bfbits_hi(u.z);
    f[6] = bfbits_lo(u.w); f[7] = bfbits_hi(u.w);
}

// ---------------- fused fp32 -> bf16 convert for q,k,v ----------------
__global__ __launch_bounds__(256) void cvt3(const float* __restrict__ q,
                                            const float* __restrict__ k,
                                            const float* __restrict__ v,
                                            u16* __restrict__ Q, u16* __restrict__ K,
                                            u16* __restrict__ V) {
    const int z = blockIdx.z;
    const float* __restrict__ src = (z == 0) ? q : (z == 1) ? k : v;
    u16* __restrict__ dst = (z == 0) ? Q : (z == 1) ? K : V;
    const size_t i = ((size_t)blockIdx.x * 256 + threadIdx.x) * 8;
    float4 a = *(const float4*)(src + i);
    float4 b = *(const float4*)(src + i + 4);
    uint4 o;
    o.x = pk_bf2(a.x, a.y); o.y = pk_bf2(a.z, a.w);
    o.z = pk_bf2(b.x, b.y); o.w = pk_bf2(b.z, b.w);
    *(uint4*)(dst + i) = o;
}

// ---------------- weight transpose + convert: WT[n][k] = bf16(W[k][n]) ----------------
struct WtArgs { const float* W[4]; u16* WT[4]; };

__global__ __launch_bounds__(256) void wtrans(WtArgs a) {
    const int z = blockIdx.z;
    const float* __restrict__ W = a.W[z];
    u16* __restrict__ WT = a.WT[z];
    __shared__ float tile[64][65];
    const int n0 = blockIdx.x * 64, k0 = blockIdx.y * 64;
    const int tid = threadIdx.x;
    const int r = tid >> 6, c = tid & 63;
    #pragma unroll
    for (int p = 0; p < 16; ++p) {
        const int row = p * 4 + r;
        tile[row][c] = W[(size_t)(k0 + row) * 1024 + n0 + c];
    }
    __syncthreads();
    #pragma unroll
    for (int p = 0; p < 16; ++p) {
        const int row = p * 4 + r;   // n index within tile
        WT[(size_t)(n0 + row) * 1024 + k0 + c] = f2bf_rne(tile[c][row]);
    }
}

// ---------------- GEMM: C[m][n] = sum_k A[m][k] * BT[n][k] + bias[n] ----------------
struct GemmArgs { const void* A[3]; const void* BT[3]; const void* bias[3]; void* C[3]; };

template<bool A_F32, bool OUT_F32>
__global__ __launch_bounds__(256, 2)
void gemm_bt(GemmArgs ga, int M, int N, int K) {
    __shared__ u16 As[128 * 32];
    __shared__ u16 Bs[128 * 32];
    const int z = blockIdx.z;
    const u16*   __restrict__ BT   = (const u16*)ga.BT[z];
    const float* __restrict__ bias = (const float*)ga.bias[z];
    const int tid = threadIdx.x;
    const int lane = tid & 63;
    const int wave = tid >> 6;
    const int m0 = blockIdx.y * 128;
    const int n0 = blockIdx.x * 128;

    f32x4 acc[4][4] = {};

    const int srow = lane >> 2;        // row within 16-row chunk (bf16 gl_lds path)
    const int scol = (lane & 3) * 8;   // col within 32 (8 bf16 = 16B)

    for (int k0 = 0; k0 < K; k0 += 32) {
        // ---- stage B-tile (128x32 bf16) via async global->LDS
        #pragma unroll
        for (int cc = 0; cc < 2; ++cc) {
            const int chunk = cc * 4 + wave;
            gl_lds16(BT + (size_t)(n0 + chunk * 16 + srow) * K + (k0 + scol),
                     &Bs[chunk * 512]);
        }
        // ---- stage A-tile
        if constexpr (A_F32) {
            const float* __restrict__ A = (const float*)ga.A[z];
            float4 av[4];
            #pragma unroll
            for (int cc = 0; cc < 4; ++cc) {
                const int e = (cc * 256 + tid) * 4;
                av[cc] = *(const float4*)(A + (size_t)(m0 + (e >> 5)) * K + (k0 + (e & 31)));
            }
            #pragma unroll
            for (int cc = 0; cc < 4; ++cc) {
                const int e = (cc * 256 + tid) * 4;
                uint2 pk;
                pk.x = pk_bf2(av[cc].x, av[cc].y);
                pk.y = pk_bf2(av[cc].z, av[cc].w);
                *(uint2*)&As[(e >> 5) * 32 + (e & 31)] = pk;
            }
        } else {
            const u16* __restrict__ A = (const u16*)ga.A[z];
            #pragma unroll
            for (int cc = 0; cc < 2; ++cc) {
                const int chunk = cc * 4 + wave;
                gl_lds16(A + (size_t)(m0 + chunk * 16 + srow) * K + (k0 + scol),
                         &As[chunk * 512]);
            }
        }
        __syncthreads();

        // ---- fragments + MFMA
        const int wm = (wave >> 1) * 64;
        const int wn = (wave & 1) * 64;
        const int fr = lane & 15;
        const int fk = (lane >> 4) * 8;
        bf16x8 af[4], bfr[4];
        #pragma unroll
        for (int i = 0; i < 4; ++i) af[i]  = *(const bf16x8*)&As[(wm + i * 16 + fr) * 32 + fk];
        #pragma unroll
        for (int j = 0; j < 4; ++j) bfr[j] = *(const bf16x8*)&Bs[(wn + j * 16 + fr) * 32 + fk];
        #pragma unroll
        for (int i = 0; i < 4; ++i)
            #pragma unroll
            for (int j = 0; j < 4; ++j)
                acc[i][j] = __builtin_amdgcn_mfma_f32_16x16x32_bf16(af[i], bfr[j], acc[i][j], 0, 0, 0);
        __syncthreads();
    }

    // ---- epilogue: C/D layout col=lane&15, row=(lane>>4)*4+r
    const int wm = (wave >> 1) * 64;
    const int wn = (wave & 1) * 64;
    const int r0 = m0 + wm + (lane >> 4) * 4;
    const int c0 = n0 + wn + (lane & 15);
    #pragma unroll
    for (int j = 0; j < 4; ++j) {
        const int col = c0 + j * 16;
        const float bv = bias[col];
        #pragma unroll
        for (int i = 0; i < 4; ++i) {
            #pragma unroll
            for (int r = 0; r < 4; ++r) {
                const int row = r0 + i * 16 + r;
                const float v = acc[i][j][r] + bv;
                if constexpr (OUT_F32) ((float*)ga.C[z])[(size_t)row * N + col] = v;
                else                   ((u16*)ga.C[z])[(size_t)row * N + col] = f2bf_rne(v);
            }
        }
    }
}

// ---------------- attention over head axis, per (b, g=l/16) tile ----------------
// Q[b,l,h,d] = QL[b, h*256+g, t*64+d], l = g*16+t
__global__ __launch_bounds__(256, 2)
void attn(const u16* __restrict__ QL, const u16* __restrict__ KL, const u16* __restrict__ VL,
          u16* __restrict__ CTX, float* __restrict__ WOUT) {
    __shared__ u16 Ks[16 * 1024];
    __shared__ u16 Vs[16 * 1024];
    const int bg = blockIdx.x;
    const int b = bg >> 8, g = bg & 255;
    const int tid = threadIdx.x, lane = tid & 63, wave = tid >> 6;
    const size_t boff = (size_t)b * (4096 * 1024);

    // stage K,V tiles: 16 rows (head j) x 1024 cols; 2 chunks of 1024B per row
    for (int it = 0; it < 8; ++it) {
        const int c = it * 4 + wave;           // 0..31
        const int row = c >> 1, half = c & 1;
        const size_t gidx = boff + (size_t)(row * 256 + g) * 1024 + half * 512 + lane * 8;
        gl_lds16(KL + gidx, &Ks[c * 512]);
        gl_lds16(VL + gidx, &Vs[c * 512]);
    }
    __syncthreads();

    const int t = tid >> 4, h = tid & 15;
    // Q row into registers
    float qf[64];
    const u16* qp = QL + boff + (size_t)(h * 256 + g) * 1024 + t * 64;
    #pragma unroll
    for (int c8 = 0; c8 < 8; ++c8) {
        uint4 u = *(const uint4*)(qp + c8 * 8);
        unpack8(u, &qf[c8 * 8]);
    }
    // scores over heads j
    float s[16];
    #pragma unroll 1
    for (int j = 0; j < 16; ++j) {
        const u16* kp = &Ks[j * 1024 + t * 64];
        float a = 0.f;
        #pragma unroll
        for (int c8 = 0; c8 < 8; ++c8) {
            uint4 u = *(const uint4*)(kp + c8 * 8);
            float kf[8]; unpack8(u, kf);
            #pragma unroll
            for (int d = 0; d < 8; ++d) a = fmaf(qf[c8 * 8 + d], kf[d], a);
        }
        s[j] = a * 0.125f;  // hd^-0.5 = 1/8
    }
    // softmax over j
    float mx = s[0];
    #pragma unroll
    for (int j = 1; j < 16; ++j) mx = fmaxf(mx, s[j]);
    float w[16], sum = 0.f;
    #pragma unroll
    for (int j = 0; j < 16; ++j) { w[j] = __expf(s[j] - mx); sum += w[j]; }
    const float inv = 1.f / sum;
    #pragma unroll
    for (int j = 0; j < 16; ++j) w[j] *= inv;
    // write weights[b, l, h, j]
    {
        float4* wp = (float4*)(WOUT + ((size_t)((b * 4096 + g * 16 + t) * 16 + h) * 16));
        wp[0] = float4{w[0],  w[1],  w[2],  w[3]};
        wp[1] = float4{w[4],  w[5],  w[6],  w[7]};
        wp[2] = float4{w[8],  w[9],  w[10], w[11]};
        wp[3] = float4{w[12], w[13], w[14], w[15]};
    }
    // ctx = sum_j w[j] * V[j]
    float cx[64];
    #pragma unroll
    for (int d = 0; d < 64; ++d) cx[d] = 0.f;
    #pragma unroll 1
    for (int j = 0; j < 16; ++j) {
        const u16* vp = &Vs[j * 1024 + t * 64];
        const float wj = w[j];
        #pragma unroll
        for (int c8 = 0; c8 < 8; ++c8) {
            uint4 u = *(const uint4*)(vp + c8 * 8);
            float vf[8]; unpack8(u, vf);
            #pragma unroll
            for (int d = 0; d < 8; ++d) cx[c8 * 8 + d] = fmaf(wj, vf[d], cx[c8 * 8 + d]);
        }
    }
    // write ctx_merged[b, h*256+g, t*64+d] as bf16
    u16* cp = CTX + boff + (size_t)(h * 256 + g) * 1024 + t * 64;
    #pragma unroll
    for (int c8 = 0; c8 < 8; ++c8) {
        uint4 o;
        o.x = pk_bf2(cx[c8 * 8 + 0], cx[c8 * 8 + 1]);
        o.y = pk_bf2(cx[c8 * 8 + 2], cx[c8 * 8 + 3]);
        o.z = pk_bf2(cx[c8 * 8 + 4], cx[c8 * 8 + 5]);
        o.w = pk_bf2(cx[c8 * 8 + 6], cx[c8 * 8 + 7]);
        *(uint4*)(cp + c8 * 8) = o;
    }
}

// ---------------- host ----------------
extern "C" void kernel_launch(void* const* d_in, const int* in_sizes, int n_in,
                              void* d_out, int out_size, void* d_ws, size_t ws_size,
                              hipStream_t stream) {
    const float* q  = (const float*)d_in[0];
    const float* k  = (const float*)d_in[1];
    const float* v  = (const float*)d_in[2];
    const float* Wq = (const float*)d_in[3];
    const float* bq = (const float*)d_in[4];
    const float* Wk = (const float*)d_in[5];
    const float* bk = (const float*)d_in[6];
    const float* Wv = (const float*)d_in[7];
    const float* bv = (const float*)d_in[8];
    const float* Wo = (const float*)d_in[9];
    const float* bo = (const float*)d_in[10];

    const int M = 8 * 4096;   // 32768
    const int D = 1024;
    const size_t MD = (size_t)M * D;

    // workspace (bf16 units):
    //   WT0..WT3 (4 x 1M) | QL KL VL (3 x MD) | [big path: qb kb vb (3 x MD), CTX aliases qb]
    //   small path: CTX right after VL (277 MB total); big path needs 411 MB.
    u16* WT0 = (u16*)d_ws;
    u16* WT1 = WT0 + 1048576;
    u16* WT2 = WT1 + 1048576;
    u16* WT3 = WT2 + 1048576;
    u16* QL  = WT3 + 1048576;
    u16* KL  = QL + MD;
    u16* VL  = KL + MD;

    const size_t need_big = (4 * 1048576 + 6 * MD) * sizeof(u16);
    const bool big = ws_size >= need_big;

    float* out  = (float*)d_out;
    float* wout = out + MD;   // weights output at offset 33554432

    // 1) transpose+convert all four weight matrices
    WtArgs wa{{Wq, Wk, Wv, Wo}, {WT0, WT1, WT2, WT3}};
    wtrans<<<dim3(16, 16, 4), 256, 0, stream>>>(wa);

    u16* CTX;
    if (big) {
        u16* qb = VL + MD;
        u16* kb = qb + MD;
        u16* vb = kb + MD;
        CTX = qb;  // qb dead after QKV GEMM; attn writes CTX there
        // 2a) pre-convert q,k,v to bf16 (memory-bound, ~600 MB traffic)
        cvt3<<<dim3((int)(MD / 2048), 1, 3), 256, 0, stream>>>(q, k, v, qb, kb, vb);
        // 2b) pure-bf16 QKV projections (m97 structure: gl_lds16 for A and B)
        GemmArgs g1{{qb, kb, vb}, {WT0, WT1, WT2}, {bq, bk, bv}, {QL, KL, VL}};
        gemm_bt<false, false><<<dim3(D / 128, M / 128, 3), 256, 0, stream>>>(g1, M, D, D);
    } else {
        CTX = VL + MD;
        // fallback: in-kernel fp32->bf16 A staging
        GemmArgs g1{{q, k, v}, {WT0, WT1, WT2}, {bq, bk, bv}, {QL, KL, VL}};
        gemm_bt<true, false><<<dim3(D / 128, M / 128, 3), 256, 0, stream>>>(g1, M, D, D);
    }

    // 3) per-position head attention + softmax weights output
    attn<<<dim3(2048), 256, 0, stream>>>(QL, KL, VL, CTX, wout);

    // 4) output projection, fp32 output
    GemmArgs g2{{CTX, nullptr, nullptr}, {WT3, nullptr, nullptr}, {bo, nullptr, nullptr}, {out, nullptr, nullptr}};
    gemm_bt<false, true><<<dim3(D / 128, M / 128, 1), 256, 0, stream>>>(g2, M, D, D);
}

// Round 3
// 861.584 us; speedup vs baseline: 1.1100x; 1.0663x over previous
//
#include <hip/hip_runtime.h>
#include <hip/hip_bf16.h>
#include <stdint.h>

typedef unsigned short u16;
typedef unsigned int   u32;
typedef __attribute__((ext_vector_type(8))) short bf16x8;
typedef __attribute__((ext_vector_type(4))) float f32x4;

#define GLAS  __attribute__((address_space(1)))
#define LDSAS __attribute__((address_space(3)))

// async global->LDS, 16B per lane. LDS dest is wave-uniform base + lane*16.
__device__ __forceinline__ void gl_lds16(const void* g, void* l) {
    __builtin_amdgcn_global_load_lds((const GLAS u32*)(uintptr_t)g,
                                     (LDSAS u32*)(u32)(uintptr_t)l, 16, 0, 0);
}

// RNE fp32->bf16
__device__ __forceinline__ u16 f2bf_rne(float f) {
    u32 u = __float_as_uint(f);
    u32 r = u + 0x7fffu + ((u >> 16) & 1u);
    return (u16)(r >> 16);
}
// packed pair (v_cvt_pk_bf16_f32 on gfx950), low16 = a
__device__ __forceinline__ u32 pk_bf2(float a, float b) {
    __hip_bfloat162 h = __float22bfloat162_rn(float2{a, b});
    u32 u; __builtin_memcpy(&u, &h, 4);
    return u;
}
__device__ __forceinline__ float bfbits_lo(u32 p) { return __uint_as_float(p << 16); }
__device__ __forceinline__ float bfbits_hi(u32 p) { return __uint_as_float(p & 0xffff0000u); }

__device__ __forceinline__ void unpack8(uint4 u, float* f) {
    f[0] = bfbits_lo(u.x); f[1] = bfbits_hi(u.x);
    f[2] = bfbits_lo(u.y); f[3] = bfbits_hi(u.y);
    f[4] = bfbits_lo(u.z); f[5] = bfbits_hi(u.z);
    f[6] = bfbits_lo(u.w); f[7] = bfbits_hi(u.w);
}

// ---------------- weight transpose + convert: WT[n][k] = bf16(W[k][n]) ----------------
struct WtArgs { const float* W[4]; u16* WT[4]; };

__global__ __launch_bounds__(256) void wtrans(WtArgs a) {
    const int z = blockIdx.z;
    const float* __restrict__ W = a.W[z];
    u16* __restrict__ WT = a.WT[z];
    __shared__ float tile[64][65];
    const int n0 = blockIdx.x * 64, k0 = blockIdx.y * 64;
    const int tid = threadIdx.x;
    const int r = tid >> 6, c = tid & 63;
    #pragma unroll
    for (int p = 0; p < 16; ++p) {
        const int row = p * 4 + r;
        tile[row][c] = W[(size_t)(k0 + row) * 1024 + n0 + c];
    }
    __syncthreads();
    #pragma unroll
    for (int p = 0; p < 16; ++p) {
        const int row = p * 4 + r;   // n index within tile
        WT[(size_t)(n0 + row) * 1024 + k0 + c] = f2bf_rne(tile[c][row]);
    }
}

// ---------------- GEMM: C[m][n] = sum_k A[m][k] * BT[n][k] + bias[n] ----------------
// Flat 1D grid with XCD-aware decode: blocks with linear id ≡ x (mod 8) land on
// the same XCD (round-robin heuristic). Give each XCD partition a contiguous
// 32-m-row band, iterating the 8 n-blocks consecutively per m-row, so every A
// row is consumed entirely within one XCD's L2 -> A fetched from HBM once.
struct GemmArgs { const void* A[3]; const void* BT[3]; const void* bias[3]; void* C[3]; };

template<bool A_F32, bool OUT_F32>
__global__ __launch_bounds__(256, 2)
void gemm_bt(GemmArgs ga, int M, int N, int K) {
    __shared__ u16 As[128 * 32];
    __shared__ u16 Bs[128 * 32];
    const int L = blockIdx.x;
    const int z = L >> 11;               // 2048 blocks per z (M/128=256 x N/128=8)
    const int r = L & 2047;
    const int xcd = r & 7;
    const int slot = r >> 3;             // 0..255 within partition
    const int m0 = (xcd * 32 + (slot >> 3)) * 128;
    const int n0 = (slot & 7) * 128;

    const u16*   __restrict__ BT   = (const u16*)ga.BT[z];
    const float* __restrict__ bias = (const float*)ga.bias[z];
    const int tid = threadIdx.x;
    const int lane = tid & 63;
    const int wave = tid >> 6;

    f32x4 acc[4][4] = {};

    const int srow = lane >> 2;        // row within 16-row chunk (gl_lds path)
    const int scol = (lane & 3) * 8;   // col within 32 (8 bf16 = 16B)

    for (int k0 = 0; k0 < K; k0 += 32) {
        // ---- stage B-tile (128x32 bf16) via async global->LDS
        #pragma unroll
        for (int cc = 0; cc < 2; ++cc) {
            const int chunk = cc * 4 + wave;
            gl_lds16(BT + (size_t)(n0 + chunk * 16 + srow) * K + (k0 + scol),
                     &Bs[chunk * 512]);
        }
        // ---- stage A-tile
        if constexpr (A_F32) {
            const float* __restrict__ A = (const float*)ga.A[z];
            float4 av[4];
            #pragma unroll
            for (int cc = 0; cc < 4; ++cc) {
                const int e = (cc * 256 + tid) * 4;
                av[cc] = *(const float4*)(A + (size_t)(m0 + (e >> 5)) * K + (k0 + (e & 31)));
            }
            #pragma unroll
            for (int cc = 0; cc < 4; ++cc) {
                const int e = (cc * 256 + tid) * 4;
                uint2 pk;
                pk.x = pk_bf2(av[cc].x, av[cc].y);
                pk.y = pk_bf2(av[cc].z, av[cc].w);
                *(uint2*)&As[(e >> 5) * 32 + (e & 31)] = pk;
            }
        } else {
            const u16* __restrict__ A = (const u16*)ga.A[z];
            #pragma unroll
            for (int cc = 0; cc < 2; ++cc) {
                const int chunk = cc * 4 + wave;
                gl_lds16(A + (size_t)(m0 + chunk * 16 + srow) * K + (k0 + scol),
                         &As[chunk * 512]);
            }
        }
        __syncthreads();

        // ---- fragments + MFMA
        const int wm = (wave >> 1) * 64;
        const int wn = (wave & 1) * 64;
        const int fr = lane & 15;
        const int fk = (lane >> 4) * 8;
        bf16x8 af[4], bfr[4];
        #pragma unroll
        for (int i = 0; i < 4; ++i) af[i]  = *(const bf16x8*)&As[(wm + i * 16 + fr) * 32 + fk];
        #pragma unroll
        for (int j = 0; j < 4; ++j) bfr[j] = *(const bf16x8*)&Bs[(wn + j * 16 + fr) * 32 + fk];
        #pragma unroll
        for (int i = 0; i < 4; ++i)
            #pragma unroll
            for (int j = 0; j < 4; ++j)
                acc[i][j] = __builtin_amdgcn_mfma_f32_16x16x32_bf16(af[i], bfr[j], acc[i][j], 0, 0, 0);
        __syncthreads();
    }

    // ---- epilogue: C/D layout col=lane&15, row=(lane>>4)*4+r
    const int wm = (wave >> 1) * 64;
    const int wn = (wave & 1) * 64;
    const int r0 = m0 + wm + (lane >> 4) * 4;
    const int c0 = n0 + wn + (lane & 15);
    #pragma unroll
    for (int j = 0; j < 4; ++j) {
        const int col = c0 + j * 16;
        const float bv = bias[col];
        #pragma unroll
        for (int i = 0; i < 4; ++i) {
            #pragma unroll
            for (int rr = 0; rr < 4; ++rr) {
                const int row = r0 + i * 16 + rr;
                const float v = acc[i][j][rr] + bv;
                if constexpr (OUT_F32) ((float*)ga.C[z])[(size_t)row * N + col] = v;
                else                   ((u16*)ga.C[z])[(size_t)row * N + col] = f2bf_rne(v);
            }
        }
    }
}

// ---------------- attention over head axis, per (b, g=l/16) tile ----------------
// Q[b,l,h,d] = QL[b, h*256+g, t*64+d], l = g*16+t
__global__ __launch_bounds__(256, 2)
void attn(const u16* __restrict__ QL, const u16* __restrict__ KL, const u16* __restrict__ VL,
          u16* __restrict__ CTX, float* __restrict__ WOUT) {
    __shared__ u16 Ks[16 * 1024];
    __shared__ u16 Vs[16 * 1024];
    const int bg = blockIdx.x;
    const int b = bg >> 8, g = bg & 255;
    const int tid = threadIdx.x, lane = tid & 63, wave = tid >> 6;
    const size_t boff = (size_t)b * (4096 * 1024);

    // stage K,V tiles: 16 rows (head j) x 1024 cols; 2 chunks of 1024B per row
    for (int it = 0; it < 8; ++it) {
        const int c = it * 4 + wave;           // 0..31
        const int row = c >> 1, half = c & 1;
        const size_t gidx = boff + (size_t)(row * 256 + g) * 1024 + half * 512 + lane * 8;
        gl_lds16(KL + gidx, &Ks[c * 512]);
        gl_lds16(VL + gidx, &Vs[c * 512]);
    }
    __syncthreads();

    const int t = tid >> 4, h = tid & 15;
    // Q row into registers
    float qf[64];
    const u16* qp = QL + boff + (size_t)(h * 256 + g) * 1024 + t * 64;
    #pragma unroll
    for (int c8 = 0; c8 < 8; ++c8) {
        uint4 u = *(const uint4*)(qp + c8 * 8);
        unpack8(u, &qf[c8 * 8]);
    }
    // scores over heads j
    float s[16];
    #pragma unroll 1
    for (int j = 0; j < 16; ++j) {
        const u16* kp = &Ks[j * 1024 + t * 64];
        float a = 0.f;
        #pragma unroll
        for (int c8 = 0; c8 < 8; ++c8) {
            uint4 u = *(const uint4*)(kp + c8 * 8);
            float kf[8]; unpack8(u, kf);
            #pragma unroll
            for (int d = 0; d < 8; ++d) a = fmaf(qf[c8 * 8 + d], kf[d], a);
        }
        s[j] = a * 0.125f;  // hd^-0.5 = 1/8
    }
    // softmax over j
    float mx = s[0];
    #pragma unroll
    for (int j = 1; j < 16; ++j) mx = fmaxf(mx, s[j]);
    float w[16], sum = 0.f;
    #pragma unroll
    for (int j = 0; j < 16; ++j) { w[j] = __expf(s[j] - mx); sum += w[j]; }
    const float inv = 1.f / sum;
    #pragma unroll
    for (int j = 0; j < 16; ++j) w[j] *= inv;
    // write weights[b, l, h, j]
    {
        float4* wp = (float4*)(WOUT + ((size_t)((b * 4096 + g * 16 + t) * 16 + h) * 16));
        wp[0] = float4{w[0],  w[1],  w[2],  w[3]};
        wp[1] = float4{w[4],  w[5],  w[6],  w[7]};
        wp[2] = float4{w[8],  w[9],  w[10], w[11]};
        wp[3] = float4{w[12], w[13], w[14], w[15]};
    }
    // ctx = sum_j w[j] * V[j]
    float cx[64];
    #pragma unroll
    for (int d = 0; d < 64; ++d) cx[d] = 0.f;
    #pragma unroll 1
    for (int j = 0; j < 16; ++j) {
        const u16* vp = &Vs[j * 1024 + t * 64];
        const float wj = w[j];
        #pragma unroll
        for (int c8 = 0; c8 < 8; ++c8) {
            uint4 u = *(const uint4*)(vp + c8 * 8);
            float vf[8]; unpack8(u, vf);
            #pragma unroll
            for (int d = 0; d < 8; ++d) cx[c8 * 8 + d] = fmaf(wj, vf[d], cx[c8 * 8 + d]);
        }
    }
    // write ctx_merged[b, h*256+g, t*64+d] as bf16
    u16* cp = CTX + boff + (size_t)(h * 256 + g) * 1024 + t * 64;
    #pragma unroll
    for (int c8 = 0; c8 < 8; ++c8) {
        uint4 o;
        o.x = pk_bf2(cx[c8 * 8 + 0], cx[c8 * 8 + 1]);
        o.y = pk_bf2(cx[c8 * 8 + 2], cx[c8 * 8 + 3]);
        o.z = pk_bf2(cx[c8 * 8 + 4], cx[c8 * 8 + 5]);
        o.w = pk_bf2(cx[c8 * 8 + 6], cx[c8 * 8 + 7]);
        *(uint4*)(cp + c8 * 8) = o;
    }
}

// ---------------- host ----------------
extern "C" void kernel_launch(void* const* d_in, const int* in_sizes, int n_in,
                              void* d_out, int out_size, void* d_ws, size_t ws_size,
                              hipStream_t stream) {
    const float* q  = (const float*)d_in[0];
    const float* k  = (const float*)d_in[1];
    const float* v  = (const float*)d_in[2];
    const float* Wq = (const float*)d_in[3];
    const float* bq = (const float*)d_in[4];
    const float* Wk = (const float*)d_in[5];
    const float* bk = (const float*)d_in[6];
    const float* Wv = (const float*)d_in[7];
    const float* bv = (const float*)d_in[8];
    const float* Wo = (const float*)d_in[9];
    const float* bo = (const float*)d_in[10];

    const int M = 8 * 4096;   // 32768
    const int D = 1024;
    const size_t MD = (size_t)M * D;

    // workspace (bf16 units): WT0..WT3 (4 x 1M) | QL KL VL CTX (4 x MD) = 277 MB
    u16* WT0 = (u16*)d_ws;
    u16* WT1 = WT0 + 1048576;
    u16* WT2 = WT1 + 1048576;
    u16* WT3 = WT2 + 1048576;
    u16* QL  = WT3 + 1048576;
    u16* KL  = QL + MD;
    u16* VL  = KL + MD;
    u16* CTX = VL + MD;

    float* out  = (float*)d_out;
    float* wout = out + MD;   // weights output at offset 33554432

    // 1) transpose+convert all four weight matrices
    WtArgs wa{{Wq, Wk, Wv, Wo}, {WT0, WT1, WT2, WT3}};
    wtrans<<<dim3(16, 16, 4), 256, 0, stream>>>(wa);

    // 2) QKV projections: fp32 A staged+converted in-kernel, XCD-swizzled
    GemmArgs g1{{q, k, v}, {WT0, WT1, WT2}, {bq, bk, bv}, {QL, KL, VL}};
    gemm_bt<true, false><<<dim3(3 * 2048), 256, 0, stream>>>(g1, M, D, D);

    // 3) per-position head attention + softmax weights output
    attn<<<dim3(2048), 256, 0, stream>>>(QL, KL, VL, CTX, wout);

    // 4) output projection, fp32 output, XCD-swizzled
    GemmArgs g2{{CTX, nullptr, nullptr}, {WT3, nullptr, nullptr}, {bo, nullptr, nullptr}, {out, nullptr, nullptr}};
    gemm_bt<false, true><<<dim3(2048), 256, 0, stream>>>(g2, M, D, D);
}